// Round 4
// baseline (675.122 us; speedup 1.0000x reference)
//
#include <hip/hip_runtime.h>
#include <hip/hip_bf16.h>

#define T_LEN 256
#define B_DIM 128
#define EMB 1024
#define HID 1024
#define NLAB 50
#define M_ROWS (T_LEN * B_DIM)   // 32768
#define N3H 3072
#define KTILES 16                // 1024 / BK=64

typedef __attribute__((ext_vector_type(8))) short short8;
typedef __attribute__((ext_vector_type(4))) float f32x4;

// ---- helpers ----
static __device__ __forceinline__ ushort f2b(float x) {
    unsigned u = __builtin_bit_cast(unsigned, x);
    unsigned lsb = (u >> 16) & 1u;
    u += 0x7fffu + lsb;
    return (ushort)(u >> 16);
}
static __device__ __forceinline__ float b2f(ushort u) {
    unsigned v = ((unsigned)u) << 16;
    return __builtin_bit_cast(float, v);
}
static __device__ __forceinline__ void gload16(const ushort* g, ushort* l) {
    __builtin_amdgcn_global_load_lds(
        (const __attribute__((address_space(1))) unsigned int*)g,
        (__attribute__((address_space(3))) unsigned int*)l,
        16, 0, 0);
}
static __device__ __forceinline__ float fast_sigmoid(float y) {
    return 1.f / (1.f + __expf(-y));
}
static __device__ __forceinline__ float fast_tanh(float y) {
    float e = __expf(2.f * y);
    return (e - 1.f) / (e + 1.f);
}

// ---- kernel 1: x = bf16(emb[sentence]), 16 rows per block ----
__global__ __launch_bounds__(256) void gather_convert(
    const int* __restrict__ sent, const float* __restrict__ emb,
    ushort* __restrict__ xb)
{
    const int row = blockIdx.x * 16 + (threadIdx.x >> 4);
    const int seg = threadIdx.x & 15;
    const size_t src = (size_t)sent[row] * EMB;
    const float4* ep = (const float4*)(emb + src);
    ushort4* op = (ushort4*)(xb + (size_t)row * EMB);
#pragma unroll
    for (int j = 0; j < 16; j++) {
        float4 v = ep[seg + j * 16];
        ushort4 o;
        o.x = f2b(v.x); o.y = f2b(v.y); o.z = f2b(v.z); o.w = f2b(v.w);
        op[seg + j * 16] = o;
    }
}

// ---- kernel 2: Wt[n][k] = bf16(W[k][n]) ----
__global__ __launch_bounds__(256) void transposeW(
    const float* __restrict__ W, ushort* __restrict__ Wt)
{
    __shared__ float tile[32][33];
    const int n0 = blockIdx.x * 32, k0 = blockIdx.y * 32;
    const int tx = threadIdx.x, ty = threadIdx.y;   // 32 x 8
#pragma unroll
    for (int j = 0; j < 32; j += 8)
        tile[ty + j][tx] = W[(size_t)(k0 + ty + j) * N3H + n0 + tx];
    __syncthreads();
#pragma unroll
    for (int j = 0; j < 32; j += 8)
        Wt[(size_t)(n0 + ty + j) * EMB + k0 + tx] = f2b(tile[tx][ty + j]);
}

// ---- kernel 3: 256x256, BK=64, 8 waves (2x4), depth-1 counted pipeline ----
// LDS granule swizzle: row r, 16B-granule g stored at slot g^(r&7) (involution).
// Stage: linear dest + inverse-swizzled global source. Read: swizzled offset.
__global__ __launch_bounds__(512, 2) void gemm256(
    const ushort* __restrict__ A, const ushort* __restrict__ Bt,
    const float* __restrict__ bias,
    ushort* __restrict__ zb, ushort* __restrict__ fb, ushort* __restrict__ ob)
{
    __shared__ ushort LDS[65536];   // 2 buffers x (A 32KB + B 32KB) = 128KB

    const int tid = threadIdx.x;
    const int lane = tid & 63;
    const int w = tid >> 6;
    const int wr = w >> 2, wc = w & 3;          // 2 x 4 wave grid, wave = 128x64
    const int l15 = lane & 15, lh = lane >> 4;

    const int wg = blockIdx.x;
    const ushort *Ab, *Bb;
    const float* bptr;
    ushort* dst;
    int rowbase, colbase, Mvalid, maxrow;
    bool use_tanh;
    if (wg < 1024) {
        const int w2 = (wg & 7) * 128 + (wg >> 3);   // XCD-chunked, nt-fastest
        const int mt = w2 >> 3, nt = w2 & 7;
        Ab = A + (size_t)mt * 256 * EMB;
        Bb = Bt + (size_t)nt * 256 * EMB;
        bptr = bias + nt * 256;
        rowbase = mt * 256; Mvalid = 256; maxrow = 255;
        if (nt < 4) { dst = zb; colbase = nt * 256; use_tanh = true; }
        else        { dst = fb; colbase = nt * 256 - 1024; use_tanh = false; }
    } else {
        const int q = wg - 1024;
        Ab = A + (size_t)(M_ROWS - 128) * EMB;
        Bb = Bt + (size_t)(2048 + q * 256) * EMB;
        bptr = bias + 2048 + q * 256;
        rowbase = 0; colbase = q * 256; Mvalid = 128; maxrow = 127;
        dst = ob; use_tanh = false;
    }

    // ---- stage-side: 4 A-granules + 4 B-granules per thread per K-tile ----
    // slot s = q*512+tid; r = s>>3, gs = s&7; source granule g = gs ^ (r&7)
    const ushort* pA[4];
    const ushort* pB[4];
    int dOf[4];
#pragma unroll
    for (int q = 0; q < 4; q++) {
        const int s = q * 512 + tid;
        const int r = s >> 3, gs = s & 7;
        const int g = gs ^ (r & 7);
        pA[q] = Ab + (size_t)min(r, maxrow) * EMB + g * 8;
        pB[q] = Bb + (size_t)r * EMB + g * 8;
        dOf[q] = s * 8;
    }

#define STAGE(p, t) do {                                        \
        ushort* la_ = &LDS[(p) * 32768];                        \
        ushort* lb_ = la_ + 16384;                              \
        const int ko_ = (t) * 64;                               \
        gload16(pA[0] + ko_, la_ + dOf[0]);                     \
        gload16(pA[1] + ko_, la_ + dOf[1]);                     \
        gload16(pA[2] + ko_, la_ + dOf[2]);                     \
        gload16(pA[3] + ko_, la_ + dOf[3]);                     \
        gload16(pB[0] + ko_, lb_ + dOf[0]);                     \
        gload16(pB[1] + ko_, lb_ + dOf[1]);                     \
        gload16(pB[2] + ko_, lb_ + dOf[2]);                     \
        gload16(pB[3] + ko_, lb_ + dOf[3]);                     \
    } while (0)

    // ---- read-side swizzled offsets (ushort units), ks=0; ks=1 = ^32 ----
    int offA[8], offB[4];
#pragma unroll
    for (int mi = 0; mi < 8; mi++) {
        const int r = wr * 128 + mi * 16 + l15;
        offA[mi] = r * 64 + ((lh ^ (r & 7)) * 8);   // granule g = ks*4+lh
    }
#pragma unroll
    for (int ni = 0; ni < 4; ni++) {
        const int r = wc * 64 + ni * 16 + l15;
        offB[ni] = r * 64 + ((lh ^ (r & 7)) * 8);
    }

    f32x4 acc[8][4] = {};

    // prologue: tiles 0,1; wait tile 0's 8 loads (tile 1's stay in flight)
    STAGE(0, 0);
    STAGE(1, 1);
    asm volatile("s_waitcnt vmcnt(8)" ::: "memory");
    __builtin_amdgcn_sched_barrier(0);
    __builtin_amdgcn_s_barrier();

#pragma unroll 2
    for (int t = 0; t < KTILES; ++t) {
        const int bp = (t & 1) * 32768;
        const ushort* Ablk = &LDS[bp];
        const ushort* Bblk = &LDS[bp + 16384];

        short8 a[8][2], b[4][2];
#pragma unroll
        for (int ni = 0; ni < 4; ni++) {
            b[ni][0] = *(const short8*)&Bblk[offB[ni]];
            b[ni][1] = *(const short8*)&Bblk[offB[ni] ^ 32];
        }
#pragma unroll
        for (int mi = 0; mi < 8; mi++) {
            a[mi][0] = *(const short8*)&Ablk[offA[mi]];
            a[mi][1] = *(const short8*)&Ablk[offA[mi] ^ 32];
        }
        asm volatile("s_waitcnt lgkmcnt(0)" ::: "memory");
        __builtin_amdgcn_sched_barrier(0);
        __builtin_amdgcn_s_barrier();          // all waves done reading buf
        if (t < KTILES - 2) STAGE(t & 1, t + 2);   // refill just-read buffer

        __builtin_amdgcn_s_setprio(1);
#pragma unroll
        for (int ks = 0; ks < 2; ks++)
#pragma unroll
            for (int mi = 0; mi < 8; mi++)
#pragma unroll
                for (int ni = 0; ni < 4; ni++)
                    acc[mi][ni] = __builtin_amdgcn_mfma_f32_16x16x32_bf16(
                        a[mi][ks], b[ni][ks], acc[mi][ni], 0, 0, 0);
        __builtin_amdgcn_s_setprio(0);

        if (t < KTILES - 2) {
            asm volatile("s_waitcnt vmcnt(8)" ::: "memory");   // tile t+1 resident
        } else if (t == KTILES - 2) {
            asm volatile("s_waitcnt vmcnt(0)" ::: "memory");
        }
        __builtin_amdgcn_sched_barrier(0);
        __builtin_amdgcn_s_barrier();
    }
#undef STAGE

    // ---- epilogue: act -> C tile in LDS (exactly 128KB) -> coalesced stores ----
    float bv[4];
#pragma unroll
    for (int ni = 0; ni < 4; ni++) bv[ni] = bptr[wc * 64 + ni * 16 + l15];

    __syncthreads();   // K-loop fully done; LDS reusable
#pragma unroll
    for (int mi = 0; mi < 8; mi++) {
#pragma unroll
        for (int ni = 0; ni < 4; ni++) {
            const int col = wc * 64 + ni * 16 + l15;
            const int rw = wr * 128 + mi * 16 + lh * 4;
#pragma unroll
            for (int r = 0; r < 4; r++) {
                float y = acc[mi][ni][r] + bv[ni];
                float a = use_tanh ? fast_tanh(y) : fast_sigmoid(y);
                LDS[(rw + r) * 256 + col] = f2b(a);
            }
        }
    }
    __syncthreads();
#pragma unroll
    for (int q = 0; q < 16; q++) {
        const int gg = q * 512 + tid;
        const int row = gg >> 5, cg = gg & 31;
        if (row < Mvalid) {
            short8 v = *(const short8*)&LDS[row * 256 + cg * 8];
            *(short8*)(dst + (size_t)(rowbase + row) * HID + colbase + cg * 8) = v;
        }
    }
}

// ---- kernel 4: fo-pool scan over T; h = o_last * c_last ----
__global__ __launch_bounds__(256) void fo_pool(
    const unsigned* __restrict__ z32, const unsigned* __restrict__ fz32,
    const unsigned* __restrict__ o32, float* __restrict__ hbuf)
{
    const int p = blockIdx.x * 256 + threadIdx.x;  // pairs of h
    float c0 = 0.f, c1 = 0.f;
#pragma unroll 8
    for (int t = 0; t < T_LEN; ++t) {
        unsigned zz = z32[(size_t)t * (B_DIM * HID / 2) + p];
        unsigned ff = fz32[(size_t)t * (B_DIM * HID / 2) + p];
        float z0 = b2f((ushort)(zz & 0xffffu)), z1 = b2f((ushort)(zz >> 16));
        float f0 = b2f((ushort)(ff & 0xffffu)), f1 = b2f((ushort)(ff >> 16));
        c0 += f0 * (z0 - c0);
        c1 += f1 * (z1 - c1);
    }
    unsigned oo = o32[p];
    float o0 = b2f((ushort)(oo & 0xffffu)), o1 = b2f((ushort)(oo >> 16));
    hbuf[2 * p]     = o0 * c0;
    hbuf[2 * p + 1] = o1 * c1;
}

// ---- kernel 5: logits = h @ Wout + bout; log_softmax ----
__global__ __launch_bounds__(64) void classify(
    const float* __restrict__ hbuf, const float* __restrict__ Wout,
    const float* __restrict__ bout, float* __restrict__ out)
{
    __shared__ float hs[HID];
    const int b = blockIdx.x, l = threadIdx.x;
#pragma unroll
    for (int j = 0; j < HID; j += 64) hs[j + l] = hbuf[(size_t)b * HID + j + l];
    __syncthreads();
    float acc = -1e30f;
    if (l < NLAB) {
        float s = bout[l];
#pragma unroll 4
        for (int e = 0; e < HID; e++) s += hs[e] * Wout[(size_t)e * NLAB + l];
        acc = s;
    }
    float m = acc;
#pragma unroll
    for (int off = 32; off; off >>= 1) m = fmaxf(m, __shfl_xor(m, off));
    float ex = (l < NLAB) ? expf(acc - m) : 0.f;
    float sum = ex;
#pragma unroll
    for (int off = 32; off; off >>= 1) sum += __shfl_xor(sum, off);
    if (l < NLAB) out[(size_t)b * NLAB + l] = acc - m - logf(sum);
}

extern "C" void kernel_launch(void* const* d_in, const int* in_sizes, int n_in,
                              void* d_out, int out_size, void* d_ws, size_t ws_size,
                              hipStream_t stream) {
    const int* sent = (const int*)d_in[0];
    const float* emb = (const float*)d_in[1];
    const float* W = (const float*)d_in[2];
    const float* bias = (const float*)d_in[3];
    const float* Wout = (const float*)d_in[4];
    const float* bout = (const float*)d_in[5];
    float* out = (float*)d_out;

    ushort* xb = (ushort*)d_ws;                      // 32768*1024 bf16
    ushort* Wt = xb + (size_t)M_ROWS * EMB;          // 3072*1024 bf16
    ushort* zb = Wt + (size_t)N3H * EMB;             // 32768*1024 bf16
    ushort* fb = zb + (size_t)M_ROWS * HID;          // 32768*1024 bf16
    ushort* ob = fb + (size_t)M_ROWS * HID;          // 128*1024 bf16
    float* hb = (float*)(ob + (size_t)B_DIM * HID);  // 128*1024 f32

    hipLaunchKernelGGL(gather_convert, dim3(M_ROWS / 16), dim3(256), 0, stream,
                       sent, emb, xb);
    hipLaunchKernelGGL(transposeW, dim3(N3H / 32, EMB / 32), dim3(32, 8), 0, stream,
                       W, Wt);
    hipLaunchKernelGGL(gemm256, dim3(1024 + 4), dim3(512), 0, stream,
                       xb, Wt, bias, zb, fb, ob);
    hipLaunchKernelGGL(fo_pool, dim3(B_DIM * HID / 2 / 256), dim3(256), 0, stream,
                       (const unsigned*)zb, (const unsigned*)fb,
                       (const unsigned*)ob, hb);
    hipLaunchKernelGGL(classify, dim3(B_DIM), dim3(64), 0, stream,
                       hb, Wout, bout, out);
}

// Round 5
// 496.469 us; speedup vs baseline: 1.3598x; 1.3598x over previous
//
#include <hip/hip_runtime.h>
#include <hip/hip_bf16.h>

#define T_LEN 256
#define B_DIM 128
#define EMB 1024
#define HID 1024
#define NLAB 50
#define M_ROWS (T_LEN * B_DIM)   // 32768
#define N3H 3072
#define KT 32                    // 1024 / BK=32

typedef __attribute__((ext_vector_type(8))) short short8;
typedef __attribute__((ext_vector_type(4))) float f32x4;

// ---- helpers ----
static __device__ __forceinline__ ushort f2b(float x) {
    unsigned u = __builtin_bit_cast(unsigned, x);
    unsigned lsb = (u >> 16) & 1u;
    u += 0x7fffu + lsb;
    return (ushort)(u >> 16);
}
static __device__ __forceinline__ float b2f(ushort u) {
    unsigned v = ((unsigned)u) << 16;
    return __builtin_bit_cast(float, v);
}
static __device__ __forceinline__ void gload16(const ushort* g, ushort* l) {
    __builtin_amdgcn_global_load_lds(
        (const __attribute__((address_space(1))) unsigned int*)g,
        (__attribute__((address_space(3))) unsigned int*)l,
        16, 0, 0);
}
static __device__ __forceinline__ float fast_sigmoid(float y) {
    return 1.f / (1.f + __expf(-y));
}
static __device__ __forceinline__ float fast_tanh(float y) {
    float e = __expf(2.f * y);
    return (e - 1.f) / (e + 1.f);
}

// ---- kernel 1: x = bf16(emb[sentence]), 16 rows per block ----
__global__ __launch_bounds__(256) void gather_convert(
    const int* __restrict__ sent, const float* __restrict__ emb,
    ushort* __restrict__ xb)
{
    const int row = blockIdx.x * 16 + (threadIdx.x >> 4);
    const int seg = threadIdx.x & 15;
    const size_t src = (size_t)sent[row] * EMB;
    const float4* ep = (const float4*)(emb + src);
    ushort4* op = (ushort4*)(xb + (size_t)row * EMB);
#pragma unroll
    for (int j = 0; j < 16; j++) {
        float4 v = ep[seg + j * 16];
        ushort4 o;
        o.x = f2b(v.x); o.y = f2b(v.y); o.z = f2b(v.z); o.w = f2b(v.w);
        op[seg + j * 16] = o;
    }
}

// ---- kernel 2: Wt[n][k] = bf16(W[k][n]) ----
__global__ __launch_bounds__(256) void transposeW(
    const float* __restrict__ W, ushort* __restrict__ Wt)
{
    __shared__ float tile[32][33];
    const int n0 = blockIdx.x * 32, k0 = blockIdx.y * 32;
    const int tx = threadIdx.x, ty = threadIdx.y;   // 32 x 8
#pragma unroll
    for (int j = 0; j < 32; j += 8)
        tile[ty + j][tx] = W[(size_t)(k0 + ty + j) * N3H + n0 + tx];
    __syncthreads();
#pragma unroll
    for (int j = 0; j < 32; j += 8)
        Wt[(size_t)(n0 + ty + j) * EMB + k0 + tx] = f2b(tile[tx][ty + j]);
}

// ---- kernel 3: 256x256 tile, BK=32, 8 waves, minimal 2-phase pipeline ----
// LDS per K-tile buffer: A chunked [kg][row] (kg=k-granule of 8 bf16), B same.
// Chunk c (0..1023): kg=c>>8, row=c&255; LDS index = c*8 (linear -> gload_lds ok).
// Fragment read (row r, kg=lh): offset (lh*256 + r)*8 -> 16-lane groups read
// 256B contiguous => 2 lanes/bank = conflict-free.
__global__ __launch_bounds__(512) void gemm256(
    const ushort* __restrict__ A, const ushort* __restrict__ Bt,
    const float* __restrict__ bias,
    ushort* __restrict__ zb, ushort* __restrict__ fb, ushort* __restrict__ ob)
{
    __shared__ ushort LDS[2 * 32768];   // 2 bufs x (A 16KB + B 16KB) = 128KB bytes total

    const int tid = threadIdx.x;
    const int lane = tid & 63;
    const int w = tid >> 6;
    const int wr = w >> 2, wc = w & 3;          // 2 x 4 wave grid, wave-tile 128x64
    const int l15 = lane & 15, lh = lane >> 4;

    const int wg = blockIdx.x;
    const ushort *Ab, *Bb;
    const float* bptr;
    ushort* dst;
    int rowbase, colbase, Mvalid, maxrow;
    bool use_tanh;
    if (wg < 1024) {
        const int w2 = (wg & 7) * 128 + (wg >> 3);   // XCD-chunked, nt-fastest
        const int mt = w2 >> 3, nt = w2 & 7;
        Ab = A + (size_t)mt * 256 * EMB;
        Bb = Bt + (size_t)nt * 256 * EMB;
        bptr = bias + nt * 256;
        rowbase = mt * 256; Mvalid = 256; maxrow = 255;
        if (nt < 4) { dst = zb; colbase = nt * 256; use_tanh = true; }
        else        { dst = fb; colbase = nt * 256 - 1024; use_tanh = false; }
    } else {
        const int q = wg - 1024;
        Ab = A + (size_t)(M_ROWS - 128) * EMB;
        Bb = Bt + (size_t)(2048 + q * 256) * EMB;
        bptr = bias + 2048 + q * 256;
        rowbase = 0; colbase = q * 256; Mvalid = 128; maxrow = 127;
        dst = ob; use_tanh = false;
    }

    // stage-side: chunks c0=tid, c1=tid+512 for A and for B
    const int c0 = tid, c1 = tid + 512;
    const int kgc0 = c0 >> 8, rc0 = c0 & 255;
    const int kgc1 = c1 >> 8, rc1 = c1 & 255;
    const ushort* gA0 = Ab + (size_t)min(rc0, maxrow) * EMB + kgc0 * 8;
    const ushort* gA1 = Ab + (size_t)min(rc1, maxrow) * EMB + kgc1 * 8;
    const ushort* gB0 = Bb + (size_t)rc0 * EMB + kgc0 * 8;
    const ushort* gB1 = Bb + (size_t)rc1 * EMB + kgc1 * 8;

#define STAGE(bp_, kt_) do {                                  \
        ushort* la_ = &LDS[(bp_) * 32768];                    \
        ushort* lb_ = la_ + 16384;                            \
        const int ko_ = (kt_) * 32;                           \
        gload16(gA0 + ko_, la_ + c0 * 8);                     \
        gload16(gA1 + ko_, la_ + c1 * 8);                     \
        gload16(gB0 + ko_, lb_ + c0 * 8);                     \
        gload16(gB1 + ko_, lb_ + c1 * 8);                     \
    } while (0)

    // read-side offsets (ushort units)
    int adA[8], adB[4];
#pragma unroll
    for (int mi = 0; mi < 8; mi++)
        adA[mi] = (lh * 256 + wr * 128 + mi * 16 + l15) * 8;
#pragma unroll
    for (int ni = 0; ni < 4; ni++)
        adB[ni] = (lh * 256 + wc * 64 + ni * 16 + l15) * 8;

    f32x4 acc[8][4] = {};

    STAGE(0, 0);
    asm volatile("s_waitcnt vmcnt(0)" ::: "memory");
    __builtin_amdgcn_s_barrier();
    __builtin_amdgcn_sched_barrier(0);

#pragma unroll 2
    for (int t = 0; t < KT; ++t) {
        const int buf = t & 1;
        // 1) issue next tile's staging FIRST (latency hides under reads+MFMA)
        if (t + 1 < KT) STAGE(buf ^ 1, t + 1);

        // 2) fragment reads from current buffer
        const ushort* Ablk = &LDS[buf * 32768];
        const ushort* Bblk = Ablk + 16384;
        short8 a0 = *(const short8*)&Ablk[adA[0]];
        short8 a1 = *(const short8*)&Ablk[adA[1]];
        short8 a2 = *(const short8*)&Ablk[adA[2]];
        short8 a3 = *(const short8*)&Ablk[adA[3]];
        short8 a4 = *(const short8*)&Ablk[adA[4]];
        short8 a5 = *(const short8*)&Ablk[adA[5]];
        short8 a6 = *(const short8*)&Ablk[adA[6]];
        short8 a7 = *(const short8*)&Ablk[adA[7]];
        short8 b0 = *(const short8*)&Bblk[adB[0]];
        short8 b1 = *(const short8*)&Bblk[adB[1]];
        short8 b2 = *(const short8*)&Bblk[adB[2]];
        short8 b3 = *(const short8*)&Bblk[adB[3]];
        asm volatile("s_waitcnt lgkmcnt(0)" ::: "memory");
        __builtin_amdgcn_sched_barrier(0);

        // 3) MFMA cluster
        __builtin_amdgcn_s_setprio(1);
#define MQ(AI, ar)                                                                   \
        acc[AI][0] = __builtin_amdgcn_mfma_f32_16x16x32_bf16(ar, b0, acc[AI][0], 0,0,0); \
        acc[AI][1] = __builtin_amdgcn_mfma_f32_16x16x32_bf16(ar, b1, acc[AI][1], 0,0,0); \
        acc[AI][2] = __builtin_amdgcn_mfma_f32_16x16x32_bf16(ar, b2, acc[AI][2], 0,0,0); \
        acc[AI][3] = __builtin_amdgcn_mfma_f32_16x16x32_bf16(ar, b3, acc[AI][3], 0,0,0);
        MQ(0, a0) MQ(1, a1) MQ(2, a2) MQ(3, a3)
        MQ(4, a4) MQ(5, a5) MQ(6, a6) MQ(7, a7)
#undef MQ
        __builtin_amdgcn_s_setprio(0);

        // 4) next tile resident + one barrier per K-tile
        if (t + 1 < KT) {
            asm volatile("s_waitcnt vmcnt(0)" ::: "memory");
            __builtin_amdgcn_sched_barrier(0);
            __builtin_amdgcn_s_barrier();
            __builtin_amdgcn_sched_barrier(0);
        }
    }
#undef STAGE

    // epilogue: bias + activation + bf16 stores (R1-style, clean WRITE_SIZE)
#pragma unroll
    for (int mi = 0; mi < 8; mi++) {
#pragma unroll
        for (int ni = 0; ni < 4; ni++) {
            const int nb = wc * 64 + ni * 16 + l15;
            const float bv = bptr[nb];
            const int rl = wr * 128 + mi * 16 + lh * 4;
#pragma unroll
            for (int r = 0; r < 4; r++) {
                if (rl + r < Mvalid) {
                    float y = acc[mi][ni][r] + bv;
                    float a = use_tanh ? fast_tanh(y) : fast_sigmoid(y);
                    dst[(size_t)(rowbase + rl + r) * HID + colbase + nb] = f2b(a);
                }
            }
        }
    }
}

// ---- kernel 4: fo-pool scan over T; h = o_last * c_last ----
__global__ __launch_bounds__(256) void fo_pool(
    const unsigned* __restrict__ z32, const unsigned* __restrict__ fz32,
    const unsigned* __restrict__ o32, float* __restrict__ hbuf)
{
    const int p = blockIdx.x * 256 + threadIdx.x;  // pairs of h
    float c0 = 0.f, c1 = 0.f;
#pragma unroll 8
    for (int t = 0; t < T_LEN; ++t) {
        unsigned zz = z32[(size_t)t * (B_DIM * HID / 2) + p];
        unsigned ff = fz32[(size_t)t * (B_DIM * HID / 2) + p];
        float z0 = b2f((ushort)(zz & 0xffffu)), z1 = b2f((ushort)(zz >> 16));
        float f0 = b2f((ushort)(ff & 0xffffu)), f1 = b2f((ushort)(ff >> 16));
        c0 += f0 * (z0 - c0);
        c1 += f1 * (z1 - c1);
    }
    unsigned oo = o32[p];
    float o0 = b2f((ushort)(oo & 0xffffu)), o1 = b2f((ushort)(oo >> 16));
    hbuf[2 * p]     = o0 * c0;
    hbuf[2 * p + 1] = o1 * c1;
}

// ---- kernel 5: logits = h @ Wout + bout; log_softmax ----
__global__ __launch_bounds__(64) void classify(
    const float* __restrict__ hbuf, const float* __restrict__ Wout,
    const float* __restrict__ bout, float* __restrict__ out)
{
    __shared__ float hs[HID];
    const int b = blockIdx.x, l = threadIdx.x;
#pragma unroll
    for (int j = 0; j < HID; j += 64) hs[j + l] = hbuf[(size_t)b * HID + j + l];
    __syncthreads();
    float acc = -1e30f;
    if (l < NLAB) {
        float s = bout[l];
#pragma unroll 4
        for (int e = 0; e < HID; e++) s += hs[e] * Wout[(size_t)e * NLAB + l];
        acc = s;
    }
    float m = acc;
#pragma unroll
    for (int off = 32; off; off >>= 1) m = fmaxf(m, __shfl_xor(m, off));
    float ex = (l < NLAB) ? expf(acc - m) : 0.f;
    float sum = ex;
#pragma unroll
    for (int off = 32; off; off >>= 1) sum += __shfl_xor(sum, off);
    if (l < NLAB) out[(size_t)b * NLAB + l] = acc - m - logf(sum);
}

extern "C" void kernel_launch(void* const* d_in, const int* in_sizes, int n_in,
                              void* d_out, int out_size, void* d_ws, size_t ws_size,
                              hipStream_t stream) {
    const int* sent = (const int*)d_in[0];
    const float* emb = (const float*)d_in[1];
    const float* W = (const float*)d_in[2];
    const float* bias = (const float*)d_in[3];
    const float* Wout = (const float*)d_in[4];
    const float* bout = (const float*)d_in[5];
    float* out = (float*)d_out;

    ushort* xb = (ushort*)d_ws;                      // 32768*1024 bf16
    ushort* Wt = xb + (size_t)M_ROWS * EMB;          // 3072*1024 bf16
    ushort* zb = Wt + (size_t)N3H * EMB;             // 32768*1024 bf16
    ushort* fb = zb + (size_t)M_ROWS * HID;          // 32768*1024 bf16
    ushort* ob = fb + (size_t)M_ROWS * HID;          // 128*1024 bf16
    float* hb = (float*)(ob + (size_t)B_DIM * HID);  // 128*1024 f32

    hipLaunchKernelGGL(gather_convert, dim3(M_ROWS / 16), dim3(256), 0, stream,
                       sent, emb, xb);
    hipLaunchKernelGGL(transposeW, dim3(N3H / 32, EMB / 32), dim3(32, 8), 0, stream,
                       W, Wt);
    hipLaunchKernelGGL(gemm256, dim3(1024 + 4), dim3(512), 0, stream,
                       xb, Wt, bias, zb, fb, ob);
    hipLaunchKernelGGL(fo_pool, dim3(B_DIM * HID / 2 / 256), dim3(256), 0, stream,
                       (const unsigned*)zb, (const unsigned*)fb,
                       (const unsigned*)ob, hb);
    hipLaunchKernelGGL(classify, dim3(B_DIM), dim3(64), 0, stream,
                       hb, Wout, bout, out);
}